// Round 4
// baseline (744.903 us; speedup 1.0000x reference)
//
#include <hip/hip_runtime.h>
#include <math.h>

#define NN 25000
#define EE 400000
#define FF 128
#define DD 16
#define HH 64
#define HIDC 128
#define OUTC 32
#define GG 64

typedef __attribute__((ext_vector_type(8))) short short8;
typedef __attribute__((ext_vector_type(4))) float f32x4;

union S8 { short8 v; unsigned short u[8]; };

__device__ __forceinline__ float silu_f(float v) {
    return v / (1.f + __expf(-v));
}

__device__ __forceinline__ unsigned short f2bf_rne(float f) {
  unsigned u = __float_as_uint(f);
  unsigned r = u + 0x7fffu + ((u >> 16) & 1u);
  return (unsigned short)(r >> 16);
}
__device__ __forceinline__ float bfbits2f(unsigned short b) {
  return __uint_as_float(((unsigned)b) << 16);
}

// ---------------- K1: P1 = X @ W[0:128,:], P2 = X @ W[128:256,:] ----------------
__global__ __launch_bounds__(256) void k_precompute(
    const float* __restrict__ X, const float* __restrict__ W,
    float* __restrict__ P1, float* __restrict__ P2) {
  __shared__ __align__(16) float xT[4][128 * 12];
  const int w = threadIdx.x >> 6, lane = threadIdx.x & 63;
  float* xt = xT[w];
  const int nb = (blockIdx.x * 4 + w) * 8;
#pragma unroll
  for (int e = 0; e < 8; ++e) {
    const int n = nb + e;
    const bool v = n < NN;
    xt[lane * 12 + e]        = v ? X[n * FF + lane] : 0.f;
    xt[(lane + 64) * 12 + e] = v ? X[n * FF + 64 + lane] : 0.f;
  }
  __syncthreads();
  float a1[8], a2[8];
#pragma unroll
  for (int e = 0; e < 8; ++e) { a1[e] = 0.f; a2[e] = 0.f; }
#pragma unroll 4
  for (int k = 0; k < 128; ++k) {
    const float wa = W[k * 64 + lane];
    const float wb = W[(128 + k) * 64 + lane];
    float xk[8];
    *(f32x4*)&xk[0] = *(const f32x4*)&xt[k * 12];
    *(f32x4*)&xk[4] = *(const f32x4*)&xt[k * 12 + 4];
#pragma unroll
    for (int e = 0; e < 8; ++e) {
      a1[e] = fmaf(xk[e], wa, a1[e]);
      a2[e] = fmaf(xk[e], wb, a2[e]);
    }
  }
#pragma unroll
  for (int e = 0; e < 8; ++e) {
    const int n = nb + e;
    if (n < NN) {
      P1[n * 64 + lane] = a1[e];
      P2[n * 64 + lane] = a2[e];
    }
  }
}

// ---------------- K2: per-edge MLP via MFMA (bf16, h hi/lo split) ----------------
// 16 edges per wave-group, 5 groups/wave, 1250 blocks x 4 waves = 400000 edges.
// All weights live in registers as MFMA B-fragments. LDS ~23KB -> 6 blocks/CU,
// all 1250 blocks co-resident (no dispatch tail).
template <bool COORD>
__global__ __launch_bounds__(256, 6) void k_edge(
    const float* __restrict__ P1, const float* __restrict__ P2,
    const float* __restrict__ pos, const float* __restrict__ eattr,
    const int* __restrict__ ei, const float* __restrict__ mlp_w,
    const float* __restrict__ edge_w, const float* __restrict__ edge_b,
    const float* __restrict__ coord_w, const float* __restrict__ coord_b,
    float* __restrict__ e_agg, float* __restrict__ cu, float* __restrict__ deg) {
  __shared__ int s_src[320], s_dst[320];
  __shared__ __align__(16) float s_hs[4][16 * 76];   // [edge][k], stride 76
  __shared__ float s_diff[4][48];
  __shared__ float s_rad[4][16];
  __shared__ float s_red[4][16];
  const int tid = threadIdx.x, w = tid >> 6, lane = tid & 63;
  const int q = lane >> 4, m = lane & 15;
  const int base = blockIdx.x * 320;
  for (int t = tid; t < 320; t += 256) {
    s_src[t] = ei[base + t];
    s_dst[t] = ei[EE + base + t];
  }
  __syncthreads();

  // ---- weight fragments (registers, per-wave) ----
  // B-layout: B[k = q*8+j][n = nc*16+m]
  S8 wB[2][4];
#pragma unroll
  for (int kc = 0; kc < 2; ++kc)
#pragma unroll
    for (int nc = 0; nc < 4; ++nc)
#pragma unroll
      for (int j = 0; j < 8; ++j)
        wB[kc][nc].u[j] = f2bf_rne(edge_w[(kc * 32 + q * 8 + j) * 64 + nc * 16 + m]);
  S8 w3B[4];
#pragma unroll
  for (int nc = 0; nc < 4; ++nc)
#pragma unroll
    for (int j = 0; j < 8; ++j)
      w3B[nc].u[j] = (lane < 32) ? f2bf_rne(mlp_w[256 * 64 + (q * 8 + j) * 64 + nc * 16 + m])
                                 : (unsigned short)0;
  float w4r[4], cwr[4], ebr[4];
#pragma unroll
  for (int nc = 0; nc < 4; ++nc) {
    w4r[nc] = mlp_w[272 * 64 + nc * 16 + m];
    ebr[nc] = edge_b[nc * 16 + m];
    cwr[nc] = COORD ? coord_w[nc * 16 + m] : 0.f;
  }
  const float cb = COORD ? coord_b[0] : 0.f;

  const int wb = w * 80;
  const int pe = (lane < 48) ? (lane / 3) : (lane - 48);  // pos-gather edge / deg edge
  const int pc = lane - (lane / 3) * 3;

  for (int g = 0; g < 5; ++g) {
    const int gb = wb + g * 16;     // index into s_src/s_dst
    const int eb0 = base + gb;      // global edge id of group start
    int dstr[4], srcr[4];
#pragma unroll
    for (int r = 0; r < 4; ++r) {
      dstr[r] = s_dst[gb + q * 4 + r];
      srcr[r] = s_src[gb + q * 4 + r];
    }
    // pos diffs (lanes 0..47: edge pe, comp pc)
    if (lane < 48) {
      const int de = s_dst[gb + pe], se = s_src[gb + pe];
      s_diff[w][lane] = pos[de * 3 + pc] - pos[se * 3 + pc];
    }
    // eattr A-fragment (K padded 16->32; lanes>=32 supply zeros)
    float ea[8] = {0.f, 0.f, 0.f, 0.f, 0.f, 0.f, 0.f, 0.f};
    if (lane < 32) {
      const float* ep = &eattr[(size_t)(eb0 + m) * DD + q * 8];
      *(f32x4*)&ea[0] = *(const f32x4*)ep;
      *(f32x4*)&ea[4] = *(const f32x4*)(ep + 4);
    }
    S8 eaA;
#pragma unroll
    for (int j = 0; j < 8; ++j) eaA.u[j] = f2bf_rne(ea[j]);
    // P1/P2 gathers in C-layout (e = q*4+r, j = nc*16+m)
    float p1g[4][4], p2g[4][4];
#pragma unroll
    for (int r = 0; r < 4; ++r)
#pragma unroll
      for (int nc = 0; nc < 4; ++nc) {
        p1g[r][nc] = P1[(size_t)dstr[r] * 64 + nc * 16 + m];
        p2g[r][nc] = P2[(size_t)srcr[r] * 64 + nc * 16 + m];
      }
    // radial per edge
    if (lane < 16) {
      const float d0 = s_diff[w][lane * 3 + 0];
      const float d1 = s_diff[w][lane * 3 + 1];
      const float d2 = s_diff[w][lane * 3 + 2];
      s_rad[w][lane] = fmaf(d0, d0, fmaf(d1, d1, d2 * d2));
    }
    float radr[4];
#pragma unroll
    for (int r = 0; r < 4; ++r) radr[r] = s_rad[w][q * 4 + r];
    // eattr @ W3 (single mfma per nc, pure bf16)
    f32x4 c3[4];
#pragma unroll
    for (int nc = 0; nc < 4; ++nc) {
      f32x4 z = {0.f, 0.f, 0.f, 0.f};
      c3[nc] = __builtin_amdgcn_mfma_f32_16x16x32_bf16(eaA.v, w3B[nc].v, z, 0, 0, 0);
    }
    // h = silu(P1[dst]+P2[src]+rad*w4 + ea@W3) -> LDS (C-layout -> [e][k])
#pragma unroll
    for (int nc = 0; nc < 4; ++nc)
#pragma unroll
      for (int r = 0; r < 4; ++r) {
        float h = p1g[r][nc] + p2g[r][nc] + radr[r] * w4r[nc] + c3[nc][r];
        h = silu_f(h);
        s_hs[w][(q * 4 + r) * 76 + nc * 16 + m] = h;
      }
    // read h as A-fragments, split hi/lo bf16
    S8 ahi[2], alo[2];
#pragma unroll
    for (int kc = 0; kc < 2; ++kc) {
      float hv[8];
      const float* hp = &s_hs[w][m * 76 + kc * 32 + q * 8];
      *(f32x4*)&hv[0] = *(const f32x4*)hp;
      *(f32x4*)&hv[4] = *(const f32x4*)(hp + 4);
#pragma unroll
      for (int j = 0; j < 8; ++j) {
        const unsigned short hb = (unsigned short)(__float_as_uint(hv[j]) >> 16);  // truncate
        ahi[kc].u[j] = hb;
        alo[kc].u[j] = f2bf_rne(hv[j] - bfbits2f(hb));
      }
    }
    // o = h @ edge_w + eb  (2-term split: hi*w + lo*w)
    f32x4 o[4];
#pragma unroll
    for (int nc = 0; nc < 4; ++nc) {
      f32x4 bi = {ebr[nc], ebr[nc], ebr[nc], ebr[nc]};
      o[nc] = bi;
    }
#pragma unroll
    for (int kc = 0; kc < 2; ++kc)
#pragma unroll
      for (int nc = 0; nc < 4; ++nc) {
        o[nc] = __builtin_amdgcn_mfma_f32_16x16x32_bf16(ahi[kc].v, wB[kc][nc].v, o[nc], 0, 0, 0);
        o[nc] = __builtin_amdgcn_mfma_f32_16x16x32_bf16(alo[kc].v, wB[kc][nc].v, o[nc], 0, 0, 0);
      }
#pragma unroll
    for (int nc = 0; nc < 4; ++nc)
#pragma unroll
      for (int r = 0; r < 4; ++r) o[nc][r] = silu_f(o[nc][r]);
    // scatter-add e_agg
#pragma unroll
    for (int r = 0; r < 4; ++r)
#pragma unroll
      for (int nc = 0; nc < 4; ++nc)
        atomicAdd(&e_agg[(size_t)dstr[r] * 64 + nc * 16 + m], o[nc][r]);
    if (COORD) {
#pragma unroll
      for (int r = 0; r < 4; ++r) {
        float v = o[0][r] * cwr[0] + o[1][r] * cwr[1] + o[2][r] * cwr[2] + o[3][r] * cwr[3];
        v += __shfl_xor(v, 1, 64);
        v += __shfl_xor(v, 2, 64);
        v += __shfl_xor(v, 4, 64);
        v += __shfl_xor(v, 8, 64);
        if (m == 0) s_red[w][q * 4 + r] = v;
      }
      if (lane < 48) {
        const float s = silu_f(s_red[w][pe] + cb);
        atomicAdd(&cu[(size_t)s_dst[gb + pe] * 3 + pc], s_diff[w][lane] * s);
      } else {
        atomicAdd(&deg[s_dst[gb + pe]], 1.f);
      }
    }
  }
}

// ---------------- K3: node MLP (+ pos update on layer 0) ----------------
template <bool L0>
__global__ __launch_bounds__(256) void k_node(
    const float* __restrict__ x_in, const float* __restrict__ e_agg,
    const float* __restrict__ nw1, const float* __restrict__ nb1,
    const float* __restrict__ nw2, const float* __restrict__ nb2,
    const float* __restrict__ pos_in, const float* __restrict__ cu,
    const float* __restrict__ deg,
    float* __restrict__ x_out, float* __restrict__ pos_out) {
  __shared__ __align__(16) float xT[4][192 * 12];
  const int w = threadIdx.x >> 6, lane = threadIdx.x & 63;
  float* xt = xT[w];
  const int nb = (blockIdx.x * 4 + w) * 8;
#pragma unroll
  for (int e = 0; e < 8; ++e) {
    const int n = nb + e;
    const bool v = n < NN;
    xt[lane * 12 + e]         = v ? x_in[n * HIDC + lane] : 0.f;
    xt[(64 + lane) * 12 + e]  = v ? x_in[n * HIDC + 64 + lane] : 0.f;
    xt[(128 + lane) * 12 + e] = v ? e_agg[n * 64 + lane] : 0.f;
  }
  __syncthreads();
  float a[8];
#pragma unroll
  for (int e = 0; e < 8; ++e) a[e] = nb1[lane];
#pragma unroll 2
  for (int k = 0; k < 192; ++k) {
    const float wv = nw1[k * 64 + lane];
    float xk[8];
    *(f32x4*)&xk[0] = *(const f32x4*)&xt[k * 12];
    *(f32x4*)&xk[4] = *(const f32x4*)&xt[k * 12 + 4];
#pragma unroll
    for (int e = 0; e < 8; ++e) a[e] = fmaf(xk[e], wv, a[e]);
  }
#pragma unroll
  for (int e = 0; e < 8; ++e) a[e] = silu_f(a[e]);
  {
    f32x4 t0 = {a[0], a[1], a[2], a[3]};
    f32x4 t1 = {a[4], a[5], a[6], a[7]};
    *(f32x4*)&xt[lane * 12]     = t0;
    *(f32x4*)&xt[lane * 12 + 4] = t1;
  }
  float olo[8], ohi[8];
#pragma unroll
  for (int e = 0; e < 8; ++e) { olo[e] = nb2[lane]; ohi[e] = nb2[64 + lane]; }
#pragma unroll 2
  for (int k = 0; k < 64; ++k) {
    const float wl = nw2[k * HIDC + lane];
    const float wh = nw2[k * HIDC + 64 + lane];
    float hk[8];
    *(f32x4*)&hk[0] = *(const f32x4*)&xt[k * 12];
    *(f32x4*)&hk[4] = *(const f32x4*)&xt[k * 12 + 4];
#pragma unroll
    for (int e = 0; e < 8; ++e) {
      olo[e] = fmaf(hk[e], wl, olo[e]);
      ohi[e] = fmaf(hk[e], wh, ohi[e]);
    }
  }
#pragma unroll
  for (int e = 0; e < 8; ++e) {
    const int n = nb + e;
    if (n < NN) {
      x_out[n * HIDC + lane]      = olo[e];
      x_out[n * HIDC + 64 + lane] = ohi[e];
    }
  }
  if (L0) {
#pragma unroll
    for (int e = 0; e < 8; ++e) {
      const int n = nb + e;
      if (n < NN && lane < 3) {
        const float dg = fmaxf(deg[n], 1.f);
        pos_out[n * 3 + lane] = pos_in[n * 3 + lane] + cu[n * 3 + lane] / dg;
      }
    }
  }
}

// ---------------- K4: graph mean-pool partials (batch is sorted) ----------------
__global__ __launch_bounds__(128) void k_pool(
    const float* __restrict__ x, const int* __restrict__ batch,
    float* __restrict__ g_sum, float* __restrict__ g_cnt) {
  const int j = threadIdx.x;
  const int n0 = blockIdx.x * 256;
  const int n1 = min(n0 + 256, NN);
  int cur = batch[n0];
  float acc = 0.f, cnt = 0.f;
  for (int n = n0; n < n1; ++n) {
    const int b = batch[n];
    if (b != cur) {
      atomicAdd(&g_sum[cur * HIDC + j], acc);
      if (j == 0) atomicAdd(&g_cnt[cur], cnt);
      acc = 0.f; cnt = 0.f; cur = b;
    }
    acc += x[n * HIDC + j];
    cnt += 1.f;
  }
  atomicAdd(&g_sum[cur * HIDC + j], acc);
  if (j == 0) atomicAdd(&g_cnt[cur], cnt);
}

// ---------------- K5: relu(mean) -> relu(@w1+b1) -> @w2+b2 ----------------
__global__ __launch_bounds__(128) void k_final(
    const float* __restrict__ g_sum, const float* __restrict__ g_cnt,
    const float* __restrict__ w1, const float* __restrict__ b1,
    const float* __restrict__ w2, const float* __restrict__ b2,
    float* __restrict__ out) {
  __shared__ float sg[128];
  __shared__ float sh[128];
  const int g = blockIdx.x, j = threadIdx.x;
  const float c = fmaxf(g_cnt[g], 1.f);
  sg[j] = fmaxf(g_sum[g * HIDC + j] / c, 0.f);
  __syncthreads();
  float a = b1[j];
  for (int k = 0; k < 128; ++k) a += sg[k] * w1[k * 128 + j];
  sh[j] = fmaxf(a, 0.f);
  __syncthreads();
  if (j < OUTC) {
    float o = b2[j];
    for (int k = 0; k < 128; ++k) o += sh[k] * w2[k * OUTC + j];
    out[g * OUTC + j] = o;
  }
}

extern "C" void kernel_launch(void* const* d_in, const int* in_sizes, int n_in,
                              void* d_out, int out_size, void* d_ws, size_t ws_size,
                              hipStream_t stream) {
  const float* x     = (const float*)d_in[0];
  const float* pos   = (const float*)d_in[1];
  const float* eattr = (const float*)d_in[2];
  const int*   ei    = (const int*)d_in[3];
  const int*   batch = (const int*)d_in[4];
  const float* mlp_w[2]   = {(const float*)d_in[5],  (const float*)d_in[14]};
  const float* edge_w[2]  = {(const float*)d_in[6],  (const float*)d_in[15]};
  const float* edge_b[2]  = {(const float*)d_in[7],  (const float*)d_in[16]};
  const float* coord_w[2] = {(const float*)d_in[8],  (const float*)d_in[17]};
  const float* coord_b[2] = {(const float*)d_in[9],  (const float*)d_in[18]};
  const float* nw1[2]     = {(const float*)d_in[10], (const float*)d_in[19]};
  const float* nb1[2]     = {(const float*)d_in[11], (const float*)d_in[20]};
  const float* nw2[2]     = {(const float*)d_in[12], (const float*)d_in[21]};
  const float* nb2[2]     = {(const float*)d_in[13], (const float*)d_in[22]};
  const float* ow1 = (const float*)d_in[23];
  const float* ob1 = (const float*)d_in[24];
  const float* ow2 = (const float*)d_in[25];
  const float* ob2 = (const float*)d_in[26];
  float* out = (float*)d_out;

  char* p = (char*)d_ws;
  auto alloc = [&](size_t bytes) {
    float* r = (float*)p;
    p += (bytes + 255) & ~(size_t)255;
    return r;
  };
  float* P1    = alloc((size_t)NN * 64 * 4);
  float* P2    = alloc((size_t)NN * 64 * 4);
  float* e_agg = alloc((size_t)NN * 64 * 4);
  float* cu    = alloc((size_t)NN * 3 * 4);
  float* deg   = alloc((size_t)NN * 4);
  float* x1    = alloc((size_t)NN * HIDC * 4);
  float* pos1  = alloc((size_t)NN * 3 * 4);
  float* g_sum = alloc((size_t)GG * HIDC * 4);
  float* g_cnt = alloc((size_t)GG * 4);
  float* x2    = P1;  // alias: P1/P2 dead after layer-1 k_edge

  const int nodeBlocks = (NN + 31) / 32;
  const int edgeBlocks = 1250;  // 1250 x 4 waves x 80 edges = 400000 exact

  (void)hipMemsetAsync(e_agg, 0, (size_t)NN * 64 * 4, stream);
  (void)hipMemsetAsync(cu,    0, (size_t)NN * 3 * 4, stream);
  (void)hipMemsetAsync(deg,   0, (size_t)NN * 4, stream);
  (void)hipMemsetAsync(g_sum, 0, (size_t)GG * HIDC * 4, stream);
  (void)hipMemsetAsync(g_cnt, 0, (size_t)GG * 4, stream);

  // ---- layer 0 ----
  k_precompute<<<nodeBlocks, 256, 0, stream>>>(x, mlp_w[0], P1, P2);
  k_edge<true><<<edgeBlocks, 256, 0, stream>>>(P1, P2, pos, eattr, ei, mlp_w[0],
      edge_w[0], edge_b[0], coord_w[0], coord_b[0], e_agg, cu, deg);
  k_node<true><<<nodeBlocks, 256, 0, stream>>>(x, e_agg, nw1[0], nb1[0],
      nw2[0], nb2[0], pos, cu, deg, x1, pos1);

  // ---- layer 1 (output pos unused -> skip coord path) ----
  (void)hipMemsetAsync(e_agg, 0, (size_t)NN * 64 * 4, stream);
  k_precompute<<<nodeBlocks, 256, 0, stream>>>(x1, mlp_w[1], P1, P2);
  k_edge<false><<<edgeBlocks, 256, 0, stream>>>(P1, P2, pos1, eattr, ei, mlp_w[1],
      edge_w[1], edge_b[1], coord_w[1], coord_b[1], e_agg, cu, deg);
  k_node<false><<<nodeBlocks, 256, 0, stream>>>(x1, e_agg, nw1[1], nb1[1],
      nw2[1], nb2[1], pos1, cu, deg, x2, pos1);

  // ---- pooling + head ----
  k_pool<<<(NN + 255) / 256, 128, 0, stream>>>(x2, batch, g_sum, g_cnt);
  k_final<<<GG, 128, 0, stream>>>(g_sum, g_cnt, ow1, ob1, ow2, ob2, out);
}

// Round 5
// 689.622 us; speedup vs baseline: 1.0802x; 1.0802x over previous
//
#include <hip/hip_runtime.h>
#include <math.h>

#define NN 25000
#define EE 400000
#define FF 128
#define DD 16
#define HH 64
#define HIDC 128
#define OUTC 32
#define GG 64

typedef __attribute__((ext_vector_type(8))) short short8;
typedef __attribute__((ext_vector_type(4))) float f32x4;

union S8 { short8 v; unsigned short u[8]; };

__device__ __forceinline__ float silu_f(float v) {
    return v / (1.f + __expf(-v));
}

__device__ __forceinline__ unsigned short f2bf_rne(float f) {
  unsigned u = __float_as_uint(f);
  unsigned r = u + 0x7fffu + ((u >> 16) & 1u);
  return (unsigned short)(r >> 16);
}
__device__ __forceinline__ float bfbits2f(unsigned short b) {
  return __uint_as_float(((unsigned)b) << 16);
}

// ---------------- K1: P1 = X @ W[0:128,:], P2 = X @ W[128:256,:] ----------------
__global__ __launch_bounds__(256) void k_precompute(
    const float* __restrict__ X, const float* __restrict__ W,
    float* __restrict__ P1, float* __restrict__ P2) {
  __shared__ __align__(16) float xT[4][128 * 12];
  const int w = threadIdx.x >> 6, lane = threadIdx.x & 63;
  float* xt = xT[w];
  const int nb = (blockIdx.x * 4 + w) * 8;
#pragma unroll
  for (int e = 0; e < 8; ++e) {
    const int n = nb + e;
    const bool v = n < NN;
    xt[lane * 12 + e]        = v ? X[n * FF + lane] : 0.f;
    xt[(lane + 64) * 12 + e] = v ? X[n * FF + 64 + lane] : 0.f;
  }
  __syncthreads();
  float a1[8], a2[8];
#pragma unroll
  for (int e = 0; e < 8; ++e) { a1[e] = 0.f; a2[e] = 0.f; }
#pragma unroll 4
  for (int k = 0; k < 128; ++k) {
    const float wa = W[k * 64 + lane];
    const float wb = W[(128 + k) * 64 + lane];
    float xk[8];
    *(f32x4*)&xk[0] = *(const f32x4*)&xt[k * 12];
    *(f32x4*)&xk[4] = *(const f32x4*)&xt[k * 12 + 4];
#pragma unroll
    for (int e = 0; e < 8; ++e) {
      a1[e] = fmaf(xk[e], wa, a1[e]);
      a2[e] = fmaf(xk[e], wb, a2[e]);
    }
  }
#pragma unroll
  for (int e = 0; e < 8; ++e) {
    const int n = nb + e;
    if (n < NN) {
      P1[n * 64 + lane] = a1[e];
      P2[n * 64 + lane] = a2[e];
    }
  }
}

// ---------------- K2: per-edge MLP via MFMA, coalesced P-gather + row atomics ----
// 16 edges/group, 5 groups/wave, 1250 blocks x 4 waves = 400000 edges.
// P1/P2 gathered directly in A-fragment layout (full 256B rows per edge at line
// granularity); o round-trips LDS so e_agg atomics are 256B-contiguous per instr.
template <bool COORD>
__global__ __launch_bounds__(256, 4) void k_edge(
    const float* __restrict__ P1, const float* __restrict__ P2,
    const float* __restrict__ pos, const float* __restrict__ eattr,
    const int* __restrict__ ei, const float* __restrict__ mlp_w,
    const float* __restrict__ edge_w, const float* __restrict__ edge_b,
    const float* __restrict__ coord_w, const float* __restrict__ coord_b,
    float* __restrict__ e_agg, float* __restrict__ cu, float* __restrict__ deg) {
  __shared__ int s_src[320], s_dst[320];
  __shared__ __align__(16) float s_hs[4][16 * 76];   // [edge][j], stride 76
  __shared__ float s_diff[4][48];
  __shared__ float s_rad[4][16];
  __shared__ float s_red[4][16];
  const int tid = threadIdx.x, w = tid >> 6, lane = tid & 63;
  const int q = lane >> 4, m = lane & 15;
  const int base = blockIdx.x * 320;
  for (int t = tid; t < 320; t += 256) {
    s_src[t] = ei[base + t];
    s_dst[t] = ei[EE + base + t];
  }
  __syncthreads();

  // ---- weight fragments (registers, per-wave) ----
  S8 wB[2][4];
#pragma unroll
  for (int kc = 0; kc < 2; ++kc)
#pragma unroll
    for (int nc = 0; nc < 4; ++nc)
#pragma unroll
      for (int j = 0; j < 8; ++j)
        wB[kc][nc].u[j] = f2bf_rne(edge_w[(kc * 32 + q * 8 + j) * 64 + nc * 16 + m]);
  S8 w3B[4];
#pragma unroll
  for (int nc = 0; nc < 4; ++nc)
#pragma unroll
    for (int j = 0; j < 8; ++j)
      w3B[nc].u[j] = (lane < 32) ? f2bf_rne(mlp_w[256 * 64 + (q * 8 + j) * 64 + nc * 16 + m])
                                 : (unsigned short)0;
  float w4r[4], cwr[4], ebr[4];
#pragma unroll
  for (int nc = 0; nc < 4; ++nc) {
    w4r[nc] = mlp_w[272 * 64 + nc * 16 + m];
    ebr[nc] = edge_b[nc * 16 + m];
    cwr[nc] = COORD ? coord_w[nc * 16 + m] : 0.f;
  }
  const float cb = COORD ? coord_b[0] : 0.f;

  const int wb = w * 80;
  const int pe = (lane < 48) ? (lane / 3) : (lane - 48);
  const int pc = lane - (lane / 3) * 3;

  for (int g = 0; g < 5; ++g) {
    const int gb = wb + g * 16;
    const int eb0 = base + gb;
    // per-lane edge for the A-gather: edge m
    const int dm = s_dst[gb + m];
    const int sm = s_src[gb + m];
    // issue P1/P2 row gathers early (A-fragment layout, full rows at line granularity)
    f32x4 p1a[2], p1b[2], p2a[2], p2b[2];
#pragma unroll
    for (int kc = 0; kc < 2; ++kc) {
      const float* pp1 = P1 + (size_t)dm * 64 + kc * 32 + q * 8;
      const float* pp2 = P2 + (size_t)sm * 64 + kc * 32 + q * 8;
      p1a[kc] = *(const f32x4*)pp1;
      p1b[kc] = *(const f32x4*)(pp1 + 4);
      p2a[kc] = *(const f32x4*)pp2;
      p2b[kc] = *(const f32x4*)(pp2 + 4);
    }
    // pos diffs
    if (lane < 48) {
      const int de = s_dst[gb + pe], se = s_src[gb + pe];
      s_diff[w][lane] = pos[de * 3 + pc] - pos[se * 3 + pc];
    }
    // eattr A-fragment (K padded 16->32)
    float ea[8] = {0.f, 0.f, 0.f, 0.f, 0.f, 0.f, 0.f, 0.f};
    if (lane < 32) {
      const float* ep = &eattr[(size_t)(eb0 + m) * DD + q * 8];
      *(f32x4*)&ea[0] = *(const f32x4*)ep;
      *(f32x4*)&ea[4] = *(const f32x4*)(ep + 4);
    }
    S8 eaA;
#pragma unroll
    for (int j = 0; j < 8; ++j) eaA.u[j] = f2bf_rne(ea[j]);
    // radial per edge
    if (lane < 16) {
      const float d0 = s_diff[w][lane * 3 + 0];
      const float d1 = s_diff[w][lane * 3 + 1];
      const float d2 = s_diff[w][lane * 3 + 2];
      s_rad[w][lane] = fmaf(d0, d0, fmaf(d1, d1, d2 * d2));
    }
    float radr[4];
#pragma unroll
    for (int r = 0; r < 4; ++r) radr[r] = s_rad[w][q * 4 + r];
    // eattr @ W3
    f32x4 c3[4];
#pragma unroll
    for (int nc = 0; nc < 4; ++nc) {
      f32x4 z = {0.f, 0.f, 0.f, 0.f};
      c3[nc] = __builtin_amdgcn_mfma_f32_16x16x32_bf16(eaA.v, w3B[nc].v, z, 0, 0, 0);
    }
    // partial (c3 + rad*w4) -> LDS in C pattern [edge][j]
#pragma unroll
    for (int nc = 0; nc < 4; ++nc)
#pragma unroll
      for (int r = 0; r < 4; ++r)
        s_hs[w][(q * 4 + r) * 76 + nc * 16 + m] = fmaf(radr[r], w4r[nc], c3[nc][r]);
    // A-stage: partial + P1 + P2, silu, hi/lo split (same-wave DS ordering)
    S8 ahi[2], alo[2];
#pragma unroll
    for (int kc = 0; kc < 2; ++kc) {
      const float* hp = &s_hs[w][m * 76 + kc * 32 + q * 8];
      f32x4 h0 = *(const f32x4*)hp;
      f32x4 h1 = *(const f32x4*)(hp + 4);
      h0 = h0 + p1a[kc] + p2a[kc];
      h1 = h1 + p1b[kc] + p2b[kc];
      float hv[8];
      *(f32x4*)&hv[0] = h0;
      *(f32x4*)&hv[4] = h1;
#pragma unroll
      for (int j = 0; j < 8; ++j) {
        const float h = silu_f(hv[j]);
        const unsigned short hb = (unsigned short)(__float_as_uint(h) >> 16);  // truncate
        ahi[kc].u[j] = hb;
        alo[kc].u[j] = f2bf_rne(h - bfbits2f(hb));
      }
    }
    // o = h @ edge_w + eb  (hi + lo terms)
    f32x4 o[4];
#pragma unroll
    for (int nc = 0; nc < 4; ++nc) {
      f32x4 bi = {ebr[nc], ebr[nc], ebr[nc], ebr[nc]};
      o[nc] = bi;
    }
#pragma unroll
    for (int kc = 0; kc < 2; ++kc)
#pragma unroll
      for (int nc = 0; nc < 4; ++nc) {
        o[nc] = __builtin_amdgcn_mfma_f32_16x16x32_bf16(ahi[kc].v, wB[kc][nc].v, o[nc], 0, 0, 0);
        o[nc] = __builtin_amdgcn_mfma_f32_16x16x32_bf16(alo[kc].v, wB[kc][nc].v, o[nc], 0, 0, 0);
      }
#pragma unroll
    for (int nc = 0; nc < 4; ++nc)
#pragma unroll
      for (int r = 0; r < 4; ++r) o[nc][r] = silu_f(o[nc][r]);
    // COORD reduction from C-layout regs (over n within each edge row)
    if (COORD) {
#pragma unroll
      for (int r = 0; r < 4; ++r) {
        float v = o[0][r] * cwr[0] + o[1][r] * cwr[1] + o[2][r] * cwr[2] + o[3][r] * cwr[3];
        v += __shfl_xor(v, 1, 64);
        v += __shfl_xor(v, 2, 64);
        v += __shfl_xor(v, 4, 64);
        v += __shfl_xor(v, 8, 64);
        if (m == 0) s_red[w][q * 4 + r] = v;
      }
    }
    // o -> LDS (C pattern), then 256B-contiguous row atomics (WAR safe: same-wave DS order)
#pragma unroll
    for (int nc = 0; nc < 4; ++nc)
#pragma unroll
      for (int r = 0; r < 4; ++r)
        s_hs[w][(q * 4 + r) * 76 + nc * 16 + m] = o[nc][r];
#pragma unroll
    for (int e = 0; e < 16; ++e) {
      const int dv = s_dst[gb + e];
      atomicAdd(&e_agg[(size_t)dv * 64 + lane], s_hs[w][e * 76 + lane]);
    }
    if (COORD) {
      if (lane < 48) {
        const float s = silu_f(s_red[w][pe] + cb);
        atomicAdd(&cu[(size_t)s_dst[gb + pe] * 3 + pc], s_diff[w][lane] * s);
      } else {
        atomicAdd(&deg[s_dst[gb + pe]], 1.f);
      }
    }
  }
}

// ---------------- K3: node MLP (+ pos update & e_agg re-zero on layer 0) --------
template <bool L0>
__global__ __launch_bounds__(256) void k_node(
    const float* __restrict__ x_in, float* __restrict__ e_agg,
    const float* __restrict__ nw1, const float* __restrict__ nb1,
    const float* __restrict__ nw2, const float* __restrict__ nb2,
    const float* __restrict__ pos_in, const float* __restrict__ cu,
    const float* __restrict__ deg,
    float* __restrict__ x_out, float* __restrict__ pos_out) {
  __shared__ __align__(16) float xT[4][192 * 12];
  const int w = threadIdx.x >> 6, lane = threadIdx.x & 63;
  float* xt = xT[w];
  const int nb = (blockIdx.x * 4 + w) * 8;
#pragma unroll
  for (int e = 0; e < 8; ++e) {
    const int n = nb + e;
    const bool v = n < NN;
    xt[lane * 12 + e]         = v ? x_in[n * HIDC + lane] : 0.f;
    xt[(64 + lane) * 12 + e]  = v ? x_in[n * HIDC + 64 + lane] : 0.f;
    xt[(128 + lane) * 12 + e] = v ? e_agg[n * 64 + lane] : 0.f;
    if (L0 && v) e_agg[n * 64 + lane] = 0.f;   // pre-zero for layer 1 (saves a memset)
  }
  __syncthreads();
  float a[8];
#pragma unroll
  for (int e = 0; e < 8; ++e) a[e] = nb1[lane];
#pragma unroll 2
  for (int k = 0; k < 192; ++k) {
    const float wv = nw1[k * 64 + lane];
    float xk[8];
    *(f32x4*)&xk[0] = *(const f32x4*)&xt[k * 12];
    *(f32x4*)&xk[4] = *(const f32x4*)&xt[k * 12 + 4];
#pragma unroll
    for (int e = 0; e < 8; ++e) a[e] = fmaf(xk[e], wv, a[e]);
  }
#pragma unroll
  for (int e = 0; e < 8; ++e) a[e] = silu_f(a[e]);
  {
    f32x4 t0 = {a[0], a[1], a[2], a[3]};
    f32x4 t1 = {a[4], a[5], a[6], a[7]};
    *(f32x4*)&xt[lane * 12]     = t0;
    *(f32x4*)&xt[lane * 12 + 4] = t1;
  }
  float olo[8], ohi[8];
#pragma unroll
  for (int e = 0; e < 8; ++e) { olo[e] = nb2[lane]; ohi[e] = nb2[64 + lane]; }
#pragma unroll 2
  for (int k = 0; k < 64; ++k) {
    const float wl = nw2[k * HIDC + lane];
    const float wh = nw2[k * HIDC + 64 + lane];
    float hk[8];
    *(f32x4*)&hk[0] = *(const f32x4*)&xt[k * 12];
    *(f32x4*)&hk[4] = *(const f32x4*)&xt[k * 12 + 4];
#pragma unroll
    for (int e = 0; e < 8; ++e) {
      olo[e] = fmaf(hk[e], wl, olo[e]);
      ohi[e] = fmaf(hk[e], wh, ohi[e]);
    }
  }
#pragma unroll
  for (int e = 0; e < 8; ++e) {
    const int n = nb + e;
    if (n < NN) {
      x_out[n * HIDC + lane]      = olo[e];
      x_out[n * HIDC + 64 + lane] = ohi[e];
    }
  }
  if (L0) {
#pragma unroll
    for (int e = 0; e < 8; ++e) {
      const int n = nb + e;
      if (n < NN && lane < 3) {
        const float dg = fmaxf(deg[n], 1.f);
        pos_out[n * 3 + lane] = pos_in[n * 3 + lane] + cu[n * 3 + lane] / dg;
      }
    }
  }
}

// ---------------- K4: graph mean-pool partials (batch is sorted) ----------------
__global__ __launch_bounds__(128) void k_pool(
    const float* __restrict__ x, const int* __restrict__ batch,
    float* __restrict__ g_sum, float* __restrict__ g_cnt) {
  const int j = threadIdx.x;
  const int n0 = blockIdx.x * 256;
  const int n1 = min(n0 + 256, NN);
  int cur = batch[n0];
  float acc = 0.f, cnt = 0.f;
  for (int n = n0; n < n1; ++n) {
    const int b = batch[n];
    if (b != cur) {
      atomicAdd(&g_sum[cur * HIDC + j], acc);
      if (j == 0) atomicAdd(&g_cnt[cur], cnt);
      acc = 0.f; cnt = 0.f; cur = b;
    }
    acc += x[n * HIDC + j];
    cnt += 1.f;
  }
  atomicAdd(&g_sum[cur * HIDC + j], acc);
  if (j == 0) atomicAdd(&g_cnt[cur], cnt);
}

// ---------------- K5: relu(mean) -> relu(@w1+b1) -> @w2+b2 ----------------
__global__ __launch_bounds__(128) void k_final(
    const float* __restrict__ g_sum, const float* __restrict__ g_cnt,
    const float* __restrict__ w1, const float* __restrict__ b1,
    const float* __restrict__ w2, const float* __restrict__ b2,
    float* __restrict__ out) {
  __shared__ float sg[128];
  __shared__ float sh[128];
  const int g = blockIdx.x, j = threadIdx.x;
  const float c = fmaxf(g_cnt[g], 1.f);
  sg[j] = fmaxf(g_sum[g * HIDC + j] / c, 0.f);
  __syncthreads();
  float a = b1[j];
  for (int k = 0; k < 128; ++k) a += sg[k] * w1[k * 128 + j];
  sh[j] = fmaxf(a, 0.f);
  __syncthreads();
  if (j < OUTC) {
    float o = b2[j];
    for (int k = 0; k < 128; ++k) o += sh[k] * w2[k * OUTC + j];
    out[g * OUTC + j] = o;
  }
}

extern "C" void kernel_launch(void* const* d_in, const int* in_sizes, int n_in,
                              void* d_out, int out_size, void* d_ws, size_t ws_size,
                              hipStream_t stream) {
  const float* x     = (const float*)d_in[0];
  const float* pos   = (const float*)d_in[1];
  const float* eattr = (const float*)d_in[2];
  const int*   ei    = (const int*)d_in[3];
  const int*   batch = (const int*)d_in[4];
  const float* mlp_w[2]   = {(const float*)d_in[5],  (const float*)d_in[14]};
  const float* edge_w[2]  = {(const float*)d_in[6],  (const float*)d_in[15]};
  const float* edge_b[2]  = {(const float*)d_in[7],  (const float*)d_in[16]};
  const float* coord_w[2] = {(const float*)d_in[8],  (const float*)d_in[17]};
  const float* coord_b[2] = {(const float*)d_in[9],  (const float*)d_in[18]};
  const float* nw1[2]     = {(const float*)d_in[10], (const float*)d_in[19]};
  const float* nb1[2]     = {(const float*)d_in[11], (const float*)d_in[20]};
  const float* nw2[2]     = {(const float*)d_in[12], (const float*)d_in[21]};
  const float* nb2[2]     = {(const float*)d_in[13], (const float*)d_in[22]};
  const float* ow1 = (const float*)d_in[23];
  const float* ob1 = (const float*)d_in[24];
  const float* ow2 = (const float*)d_in[25];
  const float* ob2 = (const float*)d_in[26];
  float* out = (float*)d_out;

  char* p = (char*)d_ws;
  auto alloc = [&](size_t bytes) {
    float* r = (float*)p;
    p += (bytes + 255) & ~(size_t)255;
    return r;
  };
  float* P1    = alloc((size_t)NN * 64 * 4);
  float* P2    = alloc((size_t)NN * 64 * 4);
  float* e_agg = alloc((size_t)NN * 64 * 4);
  float* cu    = alloc((size_t)NN * 3 * 4);
  float* deg   = alloc((size_t)NN * 4);
  float* x1    = alloc((size_t)NN * HIDC * 4);
  float* pos1  = alloc((size_t)NN * 3 * 4);
  float* g_sum = alloc((size_t)GG * HIDC * 4);
  float* g_cnt = alloc((size_t)GG * 4);
  float* x2    = P1;  // alias: P1/P2 dead after layer-1 k_edge

  const int nodeBlocks = (NN + 31) / 32;
  const int edgeBlocks = 1250;  // 1250 x 4 waves x 80 edges = 400000 exact

  (void)hipMemsetAsync(e_agg, 0, (size_t)NN * 64 * 4, stream);
  (void)hipMemsetAsync(cu,    0, (size_t)NN * 3 * 4, stream);
  (void)hipMemsetAsync(deg,   0, (size_t)NN * 4, stream);
  (void)hipMemsetAsync(g_sum, 0, (size_t)GG * HIDC * 4, stream);
  (void)hipMemsetAsync(g_cnt, 0, (size_t)GG * 4, stream);

  // ---- layer 0 ----
  k_precompute<<<nodeBlocks, 256, 0, stream>>>(x, mlp_w[0], P1, P2);
  k_edge<true><<<edgeBlocks, 256, 0, stream>>>(P1, P2, pos, eattr, ei, mlp_w[0],
      edge_w[0], edge_b[0], coord_w[0], coord_b[0], e_agg, cu, deg);
  k_node<true><<<nodeBlocks, 256, 0, stream>>>(x, e_agg, nw1[0], nb1[0],
      nw2[0], nb2[0], pos, cu, deg, x1, pos1);

  // ---- layer 1 (pos output unused -> skip coord path; e_agg pre-zeroed by k_node) ----
  k_precompute<<<nodeBlocks, 256, 0, stream>>>(x1, mlp_w[1], P1, P2);
  k_edge<false><<<edgeBlocks, 256, 0, stream>>>(P1, P2, pos1, eattr, ei, mlp_w[1],
      edge_w[1], edge_b[1], coord_w[1], coord_b[1], e_agg, cu, deg);
  k_node<false><<<nodeBlocks, 256, 0, stream>>>(x1, e_agg, nw1[1], nb1[1],
      nw2[1], nb2[1], pos1, cu, deg, x2, pos1);

  // ---- pooling + head ----
  k_pool<<<(NN + 255) / 256, 128, 0, stream>>>(x2, batch, g_sum, g_cnt);
  k_final<<<GG, 128, 0, stream>>>(g_sum, g_cnt, ow1, ob1, ow2, ob2, out);
}

// Round 6
// 652.715 us; speedup vs baseline: 1.1412x; 1.0565x over previous
//
#include <hip/hip_runtime.h>
#include <math.h>

#define NN 25000
#define EE 400000
#define FF 128
#define DD 16
#define HH 64
#define HIDC 128
#define OUTC 32
#define GG 64

typedef __attribute__((ext_vector_type(8))) short short8;
typedef __attribute__((ext_vector_type(4))) float f32x4;

union S8 { short8 v; unsigned short u[8]; };

__device__ __forceinline__ float silu_f(float v) {
    return v / (1.f + __expf(-v));
}

__device__ __forceinline__ unsigned short f2bf_rne(float f) {
  unsigned u = __float_as_uint(f);
  unsigned r = u + 0x7fffu + ((u >> 16) & 1u);
  return (unsigned short)(r >> 16);
}
__device__ __forceinline__ float bfbits2f(unsigned short b) {
  return __uint_as_float(((unsigned)b) << 16);
}

// ---------------- Sort: counting sort of edges by dst ----------------
__global__ __launch_bounds__(256) void k_hist(
    const int* __restrict__ ei, int* __restrict__ cnt) {
  const int t = blockIdx.x * 256 + threadIdx.x;
  if (t < EE) atomicAdd(&cnt[ei[EE + t]], 1);
}

// single block, 1024 threads: exclusive prefix sum -> row_ptr & next
__global__ __launch_bounds__(1024) void k_scan(
    const int* __restrict__ cnt, int* __restrict__ row_ptr, int* __restrict__ next) {
  __shared__ int s[1024];
  const int t = threadIdx.x;
  const int base = t * 25;
  int loc[25];
  int sum = 0;
#pragma unroll
  for (int i = 0; i < 25; ++i) {
    const int n = base + i;
    loc[i] = (n < NN) ? cnt[n] : 0;
    sum += loc[i];
  }
  s[t] = sum;
  __syncthreads();
  // Hillis-Steele inclusive scan
  for (int off = 1; off < 1024; off <<= 1) {
    const int v = (t >= off) ? s[t - off] : 0;
    __syncthreads();
    s[t] += v;
    __syncthreads();
  }
  int run = s[t] - sum;  // exclusive offset for this chunk
#pragma unroll
  for (int i = 0; i < 25; ++i) {
    const int n = base + i;
    if (n < NN) {
      row_ptr[n] = run;
      next[n] = run;
      run += loc[i];
    }
  }
  if (t == 0) row_ptr[NN] = EE;
}

__global__ __launch_bounds__(256) void k_scatter(
    const int* __restrict__ ei, int* __restrict__ next,
    int* __restrict__ sdst, int* __restrict__ ssrc, int* __restrict__ seid) {
  const int t = blockIdx.x * 256 + threadIdx.x;
  if (t < EE) {
    const int d = ei[EE + t];
    const int slot = atomicAdd(&next[d], 1);
    sdst[slot] = d;
    ssrc[slot] = ei[t];
    seid[slot] = t;
  }
}

// ---------------- K1: P1 = X @ W[0:128,:], P2 = X @ W[128:256,:] ----------------
__global__ __launch_bounds__(256) void k_precompute(
    const float* __restrict__ X, const float* __restrict__ W,
    float* __restrict__ P1, float* __restrict__ P2) {
  __shared__ __align__(16) float xT[4][128 * 12];
  const int w = threadIdx.x >> 6, lane = threadIdx.x & 63;
  float* xt = xT[w];
  const int nb = (blockIdx.x * 4 + w) * 8;
#pragma unroll
  for (int e = 0; e < 8; ++e) {
    const int n = nb + e;
    const bool v = n < NN;
    xt[lane * 12 + e]        = v ? X[n * FF + lane] : 0.f;
    xt[(lane + 64) * 12 + e] = v ? X[n * FF + 64 + lane] : 0.f;
  }
  __syncthreads();
  float a1[8], a2[8];
#pragma unroll
  for (int e = 0; e < 8; ++e) { a1[e] = 0.f; a2[e] = 0.f; }
#pragma unroll 4
  for (int k = 0; k < 128; ++k) {
    const float wa = W[k * 64 + lane];
    const float wb = W[(128 + k) * 64 + lane];
    float xk[8];
    *(f32x4*)&xk[0] = *(const f32x4*)&xt[k * 12];
    *(f32x4*)&xk[4] = *(const f32x4*)&xt[k * 12 + 4];
#pragma unroll
    for (int e = 0; e < 8; ++e) {
      a1[e] = fmaf(xk[e], wa, a1[e]);
      a2[e] = fmaf(xk[e], wb, a2[e]);
    }
  }
#pragma unroll
  for (int e = 0; e < 8; ++e) {
    const int n = nb + e;
    if (n < NN) {
      P1[n * 64 + lane] = a1[e];
      P2[n * 64 + lane] = a2[e];
    }
  }
}

// ---------------- K2: per-edge MLP via MFMA, dst-sorted + run-compressed atomics -
// Edges processed in dst-sorted order. Each wave: 80 contiguous sorted edges,
// run-compress e_agg updates (one atomic per dst-run per lane).
template <bool COORD>
__global__ __launch_bounds__(256, 4) void k_edge(
    const float* __restrict__ P1, const float* __restrict__ P2,
    const float* __restrict__ pos, const float* __restrict__ eattr,
    const int* __restrict__ sdst, const int* __restrict__ ssrc,
    const int* __restrict__ seid, const float* __restrict__ mlp_w,
    const float* __restrict__ edge_w, const float* __restrict__ edge_b,
    const float* __restrict__ coord_w, const float* __restrict__ coord_b,
    float* __restrict__ e_agg, float* __restrict__ cu) {
  __shared__ int s_src[320], s_dst[320], s_eid[320];
  __shared__ __align__(16) float s_hs[4][16 * 76];   // [edge][j], stride 76
  __shared__ float s_diff[4][48];
  __shared__ float s_rad[4][16];
  __shared__ float s_red[4][16];
  const int tid = threadIdx.x, w = tid >> 6, lane = tid & 63;
  const int q = lane >> 4, m = lane & 15;
  const int base = blockIdx.x * 320;
  for (int t = tid; t < 320; t += 256) {
    s_src[t] = ssrc[base + t];
    s_dst[t] = sdst[base + t];
    s_eid[t] = seid[base + t];
  }
  __syncthreads();

  // ---- weight fragments (registers, per-wave) ----
  S8 wB[2][4];
#pragma unroll
  for (int kc = 0; kc < 2; ++kc)
#pragma unroll
    for (int nc = 0; nc < 4; ++nc)
#pragma unroll
      for (int j = 0; j < 8; ++j)
        wB[kc][nc].u[j] = f2bf_rne(edge_w[(kc * 32 + q * 8 + j) * 64 + nc * 16 + m]);
  S8 w3B[4];
#pragma unroll
  for (int nc = 0; nc < 4; ++nc)
#pragma unroll
    for (int j = 0; j < 8; ++j)
      w3B[nc].u[j] = (lane < 32) ? f2bf_rne(mlp_w[256 * 64 + (q * 8 + j) * 64 + nc * 16 + m])
                                 : (unsigned short)0;
  float w4r[4], cwr[4], ebr[4];
#pragma unroll
  for (int nc = 0; nc < 4; ++nc) {
    w4r[nc] = mlp_w[272 * 64 + nc * 16 + m];
    ebr[nc] = edge_b[nc * 16 + m];
    cwr[nc] = COORD ? coord_w[nc * 16 + m] : 0.f;
  }
  const float cb = COORD ? coord_b[0] : 0.f;

  const int wb = w * 80;
  const int pe = (lane < 48) ? (lane / 3) : 0;
  const int pc = lane - (lane / 3) * 3;

  int cur_dst = -1;          // run-compression state (wave-uniform)
  float accum = 0.f;

  for (int g = 0; g < 5; ++g) {
    const int gb = wb + g * 16;
    const int dm = s_dst[gb + m];
    const int sm = s_src[gb + m];
    const int em = s_eid[gb + m];
    // P1/P2 row gathers in A-fragment layout
    f32x4 p1a[2], p1b[2], p2a[2], p2b[2];
#pragma unroll
    for (int kc = 0; kc < 2; ++kc) {
      const float* pp1 = P1 + (size_t)dm * 64 + kc * 32 + q * 8;
      const float* pp2 = P2 + (size_t)sm * 64 + kc * 32 + q * 8;
      p1a[kc] = *(const f32x4*)pp1;
      p1b[kc] = *(const f32x4*)(pp1 + 4);
      p2a[kc] = *(const f32x4*)pp2;
      p2b[kc] = *(const f32x4*)(pp2 + 4);
    }
    // pos diffs
    if (lane < 48) {
      const int de = s_dst[gb + pe], se = s_src[gb + pe];
      s_diff[w][lane] = pos[de * 3 + pc] - pos[se * 3 + pc];
    }
    // eattr A-fragment (K padded 16->32), gathered via original edge id
    float ea[8] = {0.f, 0.f, 0.f, 0.f, 0.f, 0.f, 0.f, 0.f};
    if (lane < 32) {
      const float* ep = &eattr[(size_t)em * DD + q * 8];
      *(f32x4*)&ea[0] = *(const f32x4*)ep;
      *(f32x4*)&ea[4] = *(const f32x4*)(ep + 4);
    }
    S8 eaA;
#pragma unroll
    for (int j = 0; j < 8; ++j) eaA.u[j] = f2bf_rne(ea[j]);
    // radial per edge
    if (lane < 16) {
      const float d0 = s_diff[w][lane * 3 + 0];
      const float d1 = s_diff[w][lane * 3 + 1];
      const float d2 = s_diff[w][lane * 3 + 2];
      s_rad[w][lane] = fmaf(d0, d0, fmaf(d1, d1, d2 * d2));
    }
    float radr[4];
#pragma unroll
    for (int r = 0; r < 4; ++r) radr[r] = s_rad[w][q * 4 + r];
    // eattr @ W3
    f32x4 c3[4];
#pragma unroll
    for (int nc = 0; nc < 4; ++nc) {
      f32x4 z = {0.f, 0.f, 0.f, 0.f};
      c3[nc] = __builtin_amdgcn_mfma_f32_16x16x32_bf16(eaA.v, w3B[nc].v, z, 0, 0, 0);
    }
    // partial (c3 + rad*w4) -> LDS in C pattern [edge][j]
#pragma unroll
    for (int nc = 0; nc < 4; ++nc)
#pragma unroll
      for (int r = 0; r < 4; ++r)
        s_hs[w][(q * 4 + r) * 76 + nc * 16 + m] = fmaf(radr[r], w4r[nc], c3[nc][r]);
    // A-stage: partial + P1 + P2, silu, hi/lo split
    S8 ahi[2], alo[2];
#pragma unroll
    for (int kc = 0; kc < 2; ++kc) {
      const float* hp = &s_hs[w][m * 76 + kc * 32 + q * 8];
      f32x4 h0 = *(const f32x4*)hp;
      f32x4 h1 = *(const f32x4*)(hp + 4);
      h0 = h0 + p1a[kc] + p2a[kc];
      h1 = h1 + p1b[kc] + p2b[kc];
      float hv[8];
      *(f32x4*)&hv[0] = h0;
      *(f32x4*)&hv[4] = h1;
#pragma unroll
      for (int j = 0; j < 8; ++j) {
        const float h = silu_f(hv[j]);
        const unsigned short hb = (unsigned short)(__float_as_uint(h) >> 16);
        ahi[kc].u[j] = hb;
        alo[kc].u[j] = f2bf_rne(h - bfbits2f(hb));
      }
    }
    // o = h @ edge_w + eb
    f32x4 o[4];
#pragma unroll
    for (int nc = 0; nc < 4; ++nc) {
      f32x4 bi = {ebr[nc], ebr[nc], ebr[nc], ebr[nc]};
      o[nc] = bi;
    }
#pragma unroll
    for (int kc = 0; kc < 2; ++kc)
#pragma unroll
      for (int nc = 0; nc < 4; ++nc) {
        o[nc] = __builtin_amdgcn_mfma_f32_16x16x32_bf16(ahi[kc].v, wB[kc][nc].v, o[nc], 0, 0, 0);
        o[nc] = __builtin_amdgcn_mfma_f32_16x16x32_bf16(alo[kc].v, wB[kc][nc].v, o[nc], 0, 0, 0);
      }
#pragma unroll
    for (int nc = 0; nc < 4; ++nc)
#pragma unroll
      for (int r = 0; r < 4; ++r) o[nc][r] = silu_f(o[nc][r]);
    // COORD reduction from C-layout regs
    if (COORD) {
#pragma unroll
      for (int r = 0; r < 4; ++r) {
        float v = o[0][r] * cwr[0] + o[1][r] * cwr[1] + o[2][r] * cwr[2] + o[3][r] * cwr[3];
        v += __shfl_xor(v, 1, 64);
        v += __shfl_xor(v, 2, 64);
        v += __shfl_xor(v, 4, 64);
        v += __shfl_xor(v, 8, 64);
        if (m == 0) s_red[w][q * 4 + r] = v;
      }
    }
    // o -> LDS (C pattern), then run-compressed row accumulation (dst-sorted)
#pragma unroll
    for (int nc = 0; nc < 4; ++nc)
#pragma unroll
      for (int r = 0; r < 4; ++r)
        s_hs[w][(q * 4 + r) * 76 + nc * 16 + m] = o[nc][r];
    for (int e = 0; e < 16; ++e) {
      const int dv = s_dst[gb + e];        // wave-uniform
      const float v = s_hs[w][e * 76 + lane];
      if (dv == cur_dst) {
        accum += v;
      } else {
        if (cur_dst >= 0) atomicAdd(&e_agg[(size_t)cur_dst * 64 + lane], accum);
        cur_dst = dv;
        accum = v;
      }
    }
    if (COORD) {
      if (lane < 48) {
        const float s = silu_f(s_red[w][pe] + cb);
        atomicAdd(&cu[(size_t)s_dst[gb + pe] * 3 + pc], s_diff[w][lane] * s);
      }
    }
  }
  if (cur_dst >= 0) atomicAdd(&e_agg[(size_t)cur_dst * 64 + lane], accum);
}

// ---------------- K3: node MLP (+ pos update & e_agg re-zero on layer 0) --------
template <bool L0>
__global__ __launch_bounds__(256) void k_node(
    const float* __restrict__ x_in, float* __restrict__ e_agg,
    const float* __restrict__ nw1, const float* __restrict__ nb1,
    const float* __restrict__ nw2, const float* __restrict__ nb2,
    const float* __restrict__ pos_in, const float* __restrict__ cu,
    const int* __restrict__ row_ptr,
    float* __restrict__ x_out, float* __restrict__ pos_out) {
  __shared__ __align__(16) float xT[4][192 * 12];
  const int w = threadIdx.x >> 6, lane = threadIdx.x & 63;
  float* xt = xT[w];
  const int nb = (blockIdx.x * 4 + w) * 8;
#pragma unroll
  for (int e = 0; e < 8; ++e) {
    const int n = nb + e;
    const bool v = n < NN;
    xt[lane * 12 + e]         = v ? x_in[n * HIDC + lane] : 0.f;
    xt[(64 + lane) * 12 + e]  = v ? x_in[n * HIDC + 64 + lane] : 0.f;
    xt[(128 + lane) * 12 + e] = v ? e_agg[n * 64 + lane] : 0.f;
    if (L0 && v) e_agg[n * 64 + lane] = 0.f;   // pre-zero for layer 1
  }
  __syncthreads();
  float a[8];
#pragma unroll
  for (int e = 0; e < 8; ++e) a[e] = nb1[lane];
#pragma unroll 2
  for (int k = 0; k < 192; ++k) {
    const float wv = nw1[k * 64 + lane];
    float xk[8];
    *(f32x4*)&xk[0] = *(const f32x4*)&xt[k * 12];
    *(f32x4*)&xk[4] = *(const f32x4*)&xt[k * 12 + 4];
#pragma unroll
    for (int e = 0; e < 8; ++e) a[e] = fmaf(xk[e], wv, a[e]);
  }
#pragma unroll
  for (int e = 0; e < 8; ++e) a[e] = silu_f(a[e]);
  {
    f32x4 t0 = {a[0], a[1], a[2], a[3]};
    f32x4 t1 = {a[4], a[5], a[6], a[7]};
    *(f32x4*)&xt[lane * 12]     = t0;
    *(f32x4*)&xt[lane * 12 + 4] = t1;
  }
  float olo[8], ohi[8];
#pragma unroll
  for (int e = 0; e < 8; ++e) { olo[e] = nb2[lane]; ohi[e] = nb2[64 + lane]; }
#pragma unroll 2
  for (int k = 0; k < 64; ++k) {
    const float wl = nw2[k * HIDC + lane];
    const float wh = nw2[k * HIDC + 64 + lane];
    float hk[8];
    *(f32x4*)&hk[0] = *(const f32x4*)&xt[k * 12];
    *(f32x4*)&hk[4] = *(const f32x4*)&xt[k * 12 + 4];
#pragma unroll
    for (int e = 0; e < 8; ++e) {
      olo[e] = fmaf(hk[e], wl, olo[e]);
      ohi[e] = fmaf(hk[e], wh, ohi[e]);
    }
  }
#pragma unroll
  for (int e = 0; e < 8; ++e) {
    const int n = nb + e;
    if (n < NN) {
      x_out[n * HIDC + lane]      = olo[e];
      x_out[n * HIDC + 64 + lane] = ohi[e];
    }
  }
  if (L0) {
#pragma unroll
    for (int e = 0; e < 8; ++e) {
      const int n = nb + e;
      if (n < NN && lane < 3) {
        const float dg = fmaxf((float)(row_ptr[n + 1] - row_ptr[n]), 1.f);
        pos_out[n * 3 + lane] = pos_in[n * 3 + lane] + cu[n * 3 + lane] / dg;
      }
    }
  }
}

// ---------------- K4: graph mean-pool partials (batch is sorted) ----------------
__global__ __launch_bounds__(128) void k_pool(
    const float* __restrict__ x, const int* __restrict__ batch,
    float* __restrict__ g_sum, float* __restrict__ g_cnt) {
  const int j = threadIdx.x;
  const int n0 = blockIdx.x * 256;
  const int n1 = min(n0 + 256, NN);
  int cur = batch[n0];
  float acc = 0.f, cnt = 0.f;
  for (int n = n0; n < n1; ++n) {
    const int b = batch[n];
    if (b != cur) {
      atomicAdd(&g_sum[cur * HIDC + j], acc);
      if (j == 0) atomicAdd(&g_cnt[cur], cnt);
      acc = 0.f; cnt = 0.f; cur = b;
    }
    acc += x[n * HIDC + j];
    cnt += 1.f;
  }
  atomicAdd(&g_sum[cur * HIDC + j], acc);
  if (j == 0) atomicAdd(&g_cnt[cur], cnt);
}

// ---------------- K5: relu(mean) -> relu(@w1+b1) -> @w2+b2 ----------------
__global__ __launch_bounds__(128) void k_final(
    const float* __restrict__ g_sum, const float* __restrict__ g_cnt,
    const float* __restrict__ w1, const float* __restrict__ b1,
    const float* __restrict__ w2, const float* __restrict__ b2,
    float* __restrict__ out) {
  __shared__ float sg[128];
  __shared__ float sh[128];
  const int g = blockIdx.x, j = threadIdx.x;
  const float c = fmaxf(g_cnt[g], 1.f);
  sg[j] = fmaxf(g_sum[g * HIDC + j] / c, 0.f);
  __syncthreads();
  float a = b1[j];
  for (int k = 0; k < 128; ++k) a += sg[k] * w1[k * 128 + j];
  sh[j] = fmaxf(a, 0.f);
  __syncthreads();
  if (j < OUTC) {
    float o = b2[j];
    for (int k = 0; k < 128; ++k) o += sh[k] * w2[k * OUTC + j];
    out[g * OUTC + j] = o;
  }
}

extern "C" void kernel_launch(void* const* d_in, const int* in_sizes, int n_in,
                              void* d_out, int out_size, void* d_ws, size_t ws_size,
                              hipStream_t stream) {
  const float* x     = (const float*)d_in[0];
  const float* pos   = (const float*)d_in[1];
  const float* eattr = (const float*)d_in[2];
  const int*   ei    = (const int*)d_in[3];
  const int*   batch = (const int*)d_in[4];
  const float* mlp_w[2]   = {(const float*)d_in[5],  (const float*)d_in[14]};
  const float* edge_w[2]  = {(const float*)d_in[6],  (const float*)d_in[15]};
  const float* edge_b[2]  = {(const float*)d_in[7],  (const float*)d_in[16]};
  const float* coord_w[2] = {(const float*)d_in[8],  (const float*)d_in[17]};
  const float* coord_b[2] = {(const float*)d_in[9],  (const float*)d_in[18]};
  const float* nw1[2]     = {(const float*)d_in[10], (const float*)d_in[19]};
  const float* nb1[2]     = {(const float*)d_in[11], (const float*)d_in[20]};
  const float* nw2[2]     = {(const float*)d_in[12], (const float*)d_in[21]};
  const float* nb2[2]     = {(const float*)d_in[13], (const float*)d_in[22]};
  const float* ow1 = (const float*)d_in[23];
  const float* ob1 = (const float*)d_in[24];
  const float* ow2 = (const float*)d_in[25];
  const float* ob2 = (const float*)d_in[26];
  float* out = (float*)d_out;

  char* p = (char*)d_ws;
  auto alloc = [&](size_t bytes) {
    void* r = (void*)p;
    p += (bytes + 255) & ~(size_t)255;
    return r;
  };
  float* P1    = (float*)alloc((size_t)NN * 64 * 4);
  float* P2    = (float*)alloc((size_t)NN * 64 * 4);
  float* e_agg = (float*)alloc((size_t)NN * 64 * 4);
  float* cu    = (float*)alloc((size_t)NN * 3 * 4);
  float* x1    = (float*)alloc((size_t)NN * HIDC * 4);
  float* pos1  = (float*)alloc((size_t)NN * 3 * 4);
  float* g_sum = (float*)alloc((size_t)GG * HIDC * 4);
  float* g_cnt = (float*)alloc((size_t)GG * 4);
  int* cnt     = (int*)alloc((size_t)NN * 4);
  int* row_ptr = (int*)alloc((size_t)(NN + 1) * 4);
  int* nxt     = (int*)alloc((size_t)NN * 4);
  int* sdst    = (int*)alloc((size_t)EE * 4);
  int* ssrc    = (int*)alloc((size_t)EE * 4);
  int* seid    = (int*)alloc((size_t)EE * 4);
  float* x2    = P1;  // alias: P1/P2 dead after layer-1 k_edge

  const int nodeBlocks = (NN + 31) / 32;
  const int edgeBlocks = 1250;  // 1250 x 4 waves x 80 edges = 400000 exact

  (void)hipMemsetAsync(e_agg, 0, (size_t)NN * 64 * 4, stream);
  (void)hipMemsetAsync(cu,    0, (size_t)NN * 3 * 4, stream);
  (void)hipMemsetAsync(g_sum, 0, (size_t)GG * HIDC * 4, stream);
  (void)hipMemsetAsync(g_cnt, 0, (size_t)GG * 4, stream);
  (void)hipMemsetAsync(cnt,   0, (size_t)NN * 4, stream);

  // ---- build dst-sorted edge order (shared by both layers) ----
  k_hist<<<(EE + 255) / 256, 256, 0, stream>>>(ei, cnt);
  k_scan<<<1, 1024, 0, stream>>>(cnt, row_ptr, nxt);
  k_scatter<<<(EE + 255) / 256, 256, 0, stream>>>(ei, nxt, sdst, ssrc, seid);

  // ---- layer 0 ----
  k_precompute<<<nodeBlocks, 256, 0, stream>>>(x, mlp_w[0], P1, P2);
  k_edge<true><<<edgeBlocks, 256, 0, stream>>>(P1, P2, pos, eattr, sdst, ssrc,
      seid, mlp_w[0], edge_w[0], edge_b[0], coord_w[0], coord_b[0], e_agg, cu);
  k_node<true><<<nodeBlocks, 256, 0, stream>>>(x, e_agg, nw1[0], nb1[0],
      nw2[0], nb2[0], pos, cu, row_ptr, x1, pos1);

  // ---- layer 1 (pos output unused -> skip coord path; e_agg pre-zeroed) ----
  k_precompute<<<nodeBlocks, 256, 0, stream>>>(x1, mlp_w[1], P1, P2);
  k_edge<false><<<edgeBlocks, 256, 0, stream>>>(P1, P2, pos1, eattr, sdst, ssrc,
      seid, mlp_w[1], edge_w[1], edge_b[1], coord_w[1], coord_b[1], e_agg, cu);
  k_node<false><<<nodeBlocks, 256, 0, stream>>>(x1, e_agg, nw1[1], nb1[1],
      nw2[1], nb2[1], pos1, cu, row_ptr, x2, pos1);

  // ---- pooling + head ----
  k_pool<<<(NN + 255) / 256, 128, 0, stream>>>(x2, batch, g_sum, g_cnt);
  k_final<<<GG, 128, 0, stream>>>(g_sum, g_cnt, ow1, ob1, ow2, ob2, out);
}